// Round 11
// baseline (345.409 us; speedup 1.0000x reference)
//
#include <hip/hip_runtime.h>
#include <hip/hip_bf16.h>
#include <hip/hip_cooperative_groups.h>
#include <math.h>

// DiscretisedBNF loss, MI355X gfx950.
// R11: cooperative mega-kernel, grid 256 x 256 (1 block/CU — trivially co-resident;
//      R7's grid-512 was likely rejected by the runtime occupancy check -> silent no-op).
//      Phases (R10-proven bodies, former 512-block phases run 2 tasks/block):
//   P0 prep(A1 bf16)  -> sync -> P1 GEMM1 splitK=8 (2 tasks) -> sync ->
//   P2 reduce1(+out=0, 2 chunks) -> sync -> P3 GEMM2 splitK=8 (2 tasks) -> sync ->
//   P4 loss (4 elem/thread, row = blk)
// Abel summation (k=127 edge kept un-saturated):
//   pO = (125/256)(1+erf(z_127)) - 126/128 - (1/128) sum_{k=1..126} erf(z_k),
//   z_k = (k/64 - 1 - mu_x) / (sigma*sqrt(2)).
// Interior sum via Euler-Maclaurin midpoint (O(1)); a>1 -> direct sum (<=7 terms).

namespace cg = cooperative_groups;

typedef __bf16 bf16_t;
typedef __bf16 bf16x8 __attribute__((ext_vector_type(8)));
typedef __bf16 bf16x4 __attribute__((ext_vector_type(4)));
typedef float  f32x4  __attribute__((ext_vector_type(4)));

#define LDK 40  // LDS row stride in bf16 (32 + 8 pad): 80B rows, 16B-aligned
#define L2S -5.6438561897747248f  // log2(0.02)

// Abramowitz-Stegun 7.1.26, |abs err| <= 1.5e-7, branch-free full-range.
__device__ __forceinline__ float erf_f(float x) {
  float ax = __builtin_fabsf(x);
  float t = __builtin_amdgcn_rcpf(fmaf(0.3275911f, ax, 1.0f));
  float p = fmaf(fmaf(fmaf(fmaf(1.061405429f, t, -1.453152027f), t, 1.421413741f),
                      t, -0.284496736f), t, 0.254829592f);
  p *= t;
  float e = __expf(-ax * ax);
  float r = fmaf(-p, e, 1.0f);
  return __builtin_copysignf(r, x);
}

// R10-proven GEMM body. Computes P[256 x 32]@n0 for K-chunk at k0 (Ktiles x 32).
// P is already offset to this split's 256x2048 slab.
__device__ __forceinline__ void gemm_phase(const bf16_t* __restrict__ A, int lda,
                                           const float* __restrict__ W, int N,
                                           float* __restrict__ P, int Ktiles,
                                           int k0, int n0,
                                           bf16_t* As, bf16_t* Bs) {
  int tid = threadIdx.x;
  int lane = tid & 63, wave = tid >> 6;
  int bn = tid & 31, bkg = tid >> 5;   // B staging: n (0..31), k-group of 4 (0..7)
  int fm = lane & 15, kq = lane >> 4;  // fragment lane decode

  f32x4 acc[4][2];
#pragma unroll
  for (int i = 0; i < 4; ++i)
#pragma unroll
    for (int j = 0; j < 2; ++j) acc[i][j] = (f32x4)0.0f;

  for (int kt = 0; kt < Ktiles; ++kt) {
    int kb = k0 + kt * 32;
    // stage A: thread = row, FULL BK=32: 4 x 8 bf16
    const bf16_t* Ar = A + (size_t)tid * lda + kb;
#pragma unroll
    for (int j = 0; j < 4; ++j)
      *(bf16x8*)(&As[tid * LDK + j * 8]) = *(const bf16x8*)(Ar + j * 8);
    // stage B transposed: Bs[n][k], fp32 -> bf16 during load (4 k-values/thread)
    {
      const float* Wp = W + (size_t)(kb + bkg * 4) * N + n0 + bn;
      bf16x4 bv;
#pragma unroll
      for (int i = 0; i < 4; ++i) bv[i] = (__bf16)Wp[(size_t)i * N];
      *(bf16x4*)(&Bs[bn * LDK + bkg * 4]) = bv;
    }
    __syncthreads();
    bf16x8 aF[4], bF[2];
#pragma unroll
    for (int i = 0; i < 4; ++i)
      aF[i] = *(const bf16x8*)(&As[(wave * 64 + i * 16 + fm) * LDK + kq * 8]);
#pragma unroll
    for (int j = 0; j < 2; ++j)
      bF[j] = *(const bf16x8*)(&Bs[(j * 16 + fm) * LDK + kq * 8]);
#pragma unroll
    for (int i = 0; i < 4; ++i)
#pragma unroll
      for (int j = 0; j < 2; ++j)
        acc[i][j] = __builtin_amdgcn_mfma_f32_16x16x32_bf16(aF[i], bF[j], acc[i][j], 0, 0, 0);
    __syncthreads();
  }
  // epilogue: C/D layout col=lane&15, row=(lane>>4)*4+reg  [m89-verified]
  float* Pp = P + n0;
#pragma unroll
  for (int i = 0; i < 4; ++i) {
    int mrow = wave * 64 + i * 16 + kq * 4;
#pragma unroll
    for (int j = 0; j < 2; ++j)
#pragma unroll
      for (int r = 0; r < 4; ++r)
        Pp[(size_t)(mrow + r) * N + j * 16 + fm] = acc[i][j][r];
  }
}

__global__ __launch_bounds__(256)
void mega_k(const float* __restrict__ x, const float* __restrict__ t,
            const float* __restrict__ noise,
            const float* __restrict__ W1, const float* __restrict__ b1,
            const float* __restrict__ W2, const float* __restrict__ b2,
            float* __restrict__ out,
            bf16_t* __restrict__ A1, bf16_t* __restrict__ h,
            float* __restrict__ P1, float* __restrict__ P2) {
  cg::grid_group grid = cg::this_grid();
  __shared__ __align__(16) bf16_t smem[256 * LDK + 32 * LDK];
  bf16_t* As = smem;
  bf16_t* Bs = smem + 256 * LDK;
  int blk = blockIdx.x;   // 0..255
  int tid = threadIdx.x;

  // ---- Phase 0: prep — block b handles row b (R10 prep_k body) ----
  {
    float tv = t[blk];
    float p = exp2f(2.0f * tv * L2S);        // 1-gamma = 0.02^(2t)
    float g = 1.0f - p, gom = g * p;         // gamma, gamma*(1-gamma)
    int e = (blk * 256 + tid) * 4;
    float4 xv = *(const float4*)(x + e);
    float4 nv = *(const float4*)(noise + e);
    bf16x4 o;
    o[0] = (__bf16)fmaf(gom, nv.x, g * xv.x);
    o[1] = (__bf16)fmaf(gom, nv.y, g * xv.y);
    o[2] = (__bf16)fmaf(gom, nv.z, g * xv.z);
    o[3] = (__bf16)fmaf(gom, nv.w, g * xv.w);
    *(bf16x4*)(A1 + e) = o;
  }
  __threadfence();
  grid.sync();

  // ---- Phase 1: GEMM1 splitK=8, BN=32 — 2 tasks/block ----
#pragma unroll
  for (int it = 0; it < 2; ++it) {
    int task = blk + it * 256;             // 0..511
    int nt = task & 63, z = task >> 6;
    gemm_phase(A1, 1024, W1, 2048, P1 + (size_t)z * 524288, 4, z * 128, nt * 32, As, Bs);
  }
  __threadfence();
  grid.sync();

  // ---- Phase 2: reduce1 -> h (2 chunks/block); blk0 zeroes out ----
  if (blk == 0 && tid == 0) *out = 0.0f;   // consumed in P4 (2 grid.syncs later)
#pragma unroll
  for (int it = 0; it < 2; ++it) {
    int e = (blk * 512 + it * 256 + tid) * 4;
    int b = e >> 11, n = e & 2047;
    float4 s = *(const float4*)(P1 + e);
#pragma unroll
    for (int sp = 1; sp < 8; ++sp) {
      float4 v = *(const float4*)(P1 + (size_t)sp * 524288 + e);
      s.x += v.x; s.y += v.y; s.z += v.z; s.w += v.w;
    }
    float tv = t[b];
    float4 wl = *(const float4*)(W1 + 1024 * 2048 + n);
    float4 bb = *(const float4*)(b1 + n);
    s.x += tv * wl.x + bb.x;
    s.y += tv * wl.y + bb.y;
    s.z += tv * wl.z + bb.z;
    s.w += tv * wl.w + bb.w;
    bf16x4 o;
    o[0] = (__bf16)(s.x >= 0.f ? s.x : 0.01f * s.x);
    o[1] = (__bf16)(s.y >= 0.f ? s.y : 0.01f * s.y);
    o[2] = (__bf16)(s.z >= 0.f ? s.z : 0.01f * s.z);
    o[3] = (__bf16)(s.w >= 0.f ? s.w : 0.01f * s.w);
    *(bf16x4*)(h + e) = o;
  }
  __threadfence();
  grid.sync();

  // ---- Phase 3: GEMM2 splitK=8, BN=32 — 2 tasks/block ----
#pragma unroll
  for (int it = 0; it < 2; ++it) {
    int task = blk + it * 256;
    int nt = task & 63, z = task >> 6;
    gemm_phase(h, 2048, W2, 2048, P2 + (size_t)z * 524288, 8, z * 256, nt * 32, As, Bs);
  }
  __threadfence();
  grid.sync();

  // ---- Phase 4: loss — block b = row b, 4 elems/thread ----
  {
    float tv = t[blk];
    float om = exp2f(2.0f * tv * L2S);         // 1-gamma
    float gamma = 1.0f - om;
    float r = sqrtf(om / gamma);
    float w = 1.0f / om;                       // SIGMA1^(-2t)
    bool lowt = tv < 1e-10f;
    float accv = 0.f;
#pragma unroll
    for (int it = 0; it < 4; ++it) {
      int gid = blk * 1024 + it * 256 + tid;
      int d = it * 256 + tid;
      int base2 = blk * 2048 + d;
      float me = b2[d], lg = b2[1024 + d];
#pragma unroll
      for (int sp = 0; sp < 8; ++sp) {
        me += P2[(size_t)sp * 524288 + base2];
        lg += P2[(size_t)sp * 524288 + base2 + 1024];
      }
      float xs = x[gid], ns = noise[gid];
      float mu_x = xs + om * ns - r * me;        // mu/gamma - r*mu_eps
      float sig = r * __expf(lg);
      if (lowt) { mu_x = 0.f; sig = 1.f; }
      float invs = 0.70710678118654752f / sig;   // 1/(sigma*sqrt(2))
      float a = invs * 0.015625f;                // z step per k
      float c0 = (1.f + mu_x) * invs;            // z_k = a*k - c0
      float m64 = 64.f * (1.f + mu_x);
      float wdt = 316.78383797157331f * sig;     // 3.5/a
      float lo = m64 - wdt, hi = m64 + wdt;
      int klo = (lo < 1.f) ? 1 : ((lo > 126.f) ? 127 : (int)ceilf(lo));
      int khi = (hi < 1.f) ? 0 : ((hi > 126.f) ? 126 : (int)floorf(hi));
      float ss = (float)(126 - khi) - (float)(klo - 1);
      if (khi >= klo) {
        if (a <= 1.0f) {
          float za = fmaf(a, (float)klo - 0.5f, -c0);
          float zb = fmaf(a, (float)khi + 0.5f, -c0);
          const float ISP = 0.56418958354775628f;  // 1/sqrt(pi)
          float ea = __expf(-za * za), eb = __expf(-zb * zb);
          float Ga = fmaf(za, erf_f(za), ISP * ea);
          float Gb = fmaf(zb, erf_f(zb), ISP * eb);
          float S = (Gb - Ga) * __builtin_amdgcn_rcpf(a)
                  - a * 0.047015889f * (eb - ea);
          ss += S;
        } else {
          for (int k = klo; k <= khi; ++k) ss += erf_f(fmaf(a, (float)k, -c0));
        }
      }
      float z127 = fmaf(a, 127.f, -c0);          // k=127 edge, un-saturated
      float pO = fmaf(0.48828125f, 1.f + erf_f(z127),
                      fmaf(-0.0078125f, ss, -0.984375f));
      float df = xs - pO;
      accv = fmaf(w * df, df, accv);
    }
#pragma unroll
    for (int off = 32; off > 0; off >>= 1) accv += __shfl_down(accv, off, 64);
    float* red = (float*)smem;  // gemm phases done
    __syncthreads();
    if ((tid & 63) == 0) red[tid >> 6] = accv;
    __syncthreads();
    if (tid == 0) {
      const float SCALE = 3.9120230054281461f / 262144.0f;  // -ln(0.02)/(B*D)
      atomicAdd(out, (red[0] + red[1] + red[2] + red[3]) * SCALE);
    }
  }
}

extern "C" void kernel_launch(void* const* d_in, const int* in_sizes, int n_in,
                              void* d_out, int out_size, void* d_ws, size_t ws_size,
                              hipStream_t stream) {
  const float* x     = (const float*)d_in[0];
  const float* t     = (const float*)d_in[1];
  const float* noise = (const float*)d_in[2];
  const float* W1    = (const float*)d_in[3];
  const float* b1    = (const float*)d_in[4];
  const float* W2    = (const float*)d_in[5];
  const float* b2    = (const float*)d_in[6];
  float* out = (float*)d_out;

  // ws layout (needs ~34 MB)
  char* ws = (char*)d_ws;
  bf16_t* A1 = (bf16_t*)ws;                        // 512 KB
  bf16_t* h  = (bf16_t*)(ws + 524288);             // 1 MB
  float*  P1 = (float*)(ws + 524288 + 1048576);    // 16 MB
  float*  P2 = (float*)(ws + 524288 + 1048576 + 16777216);  // 16 MB

  void* args[] = {
    (void*)&x, (void*)&t, (void*)&noise, (void*)&W1, (void*)&b1,
    (void*)&W2, (void*)&b2, (void*)&out,
    (void*)&A1, (void*)&h, (void*)&P1, (void*)&P2
  };
  hipLaunchCooperativeKernel((void*)mega_k, dim3(256), dim3(256), args, 0, stream);
}

// Round 12
// 139.532 us; speedup vs baseline: 2.4755x; 2.4755x over previous
//
#include <hip/hip_runtime.h>
#include <hip/hip_bf16.h>
#include <math.h>

// DiscretisedBNF loss, MI355X gfx950.
// R12: R10 base + atomic split-K: gemms accumulate via native f32 atomics into single
//      C1 (2 MB) / C2 (4 MB) buffers (footprint L2/L3-resident) instead of 8 x 2 MB
//      partial slabs — kills ~50 MB of HBM partial traffic. prep_k zero-inits C1/C2.
//      5 dispatches: prep(+zero C1/C2) -> GEMM1(atomic) -> reduce1(+out=0) ->
//      GEMM2(atomic) -> loss.
// R11 post-mortem: cooperative grid.sync() ~60us/sync on this stack (250us kernel, all
//      pipes idle) — cooperative fusion abandoned.
// Abel summation (k=127 edge kept un-saturated):
//   pO = (125/256)(1+erf(z_127)) - 126/128 - (1/128) sum_{k=1..126} erf(z_k),
//   z_k = (k/64 - 1 - mu_x) / (sigma*sqrt(2)).
// Interior sum via Euler-Maclaurin midpoint (O(1)); a>1 -> direct sum (<=7 terms).

typedef __bf16 bf16_t;
typedef __bf16 bf16x8 __attribute__((ext_vector_type(8)));
typedef __bf16 bf16x4 __attribute__((ext_vector_type(4)));
typedef float  f32x4  __attribute__((ext_vector_type(4)));

#define LDK 40  // LDS row stride in bf16 (32 + 8 pad): 80B rows, 16B-aligned
#define L2S -5.6438561897747248f  // log2(0.02)

// Abramowitz-Stegun 7.1.26, |abs err| <= 1.5e-7, branch-free full-range.
__device__ __forceinline__ float erf_f(float x) {
  float ax = __builtin_fabsf(x);
  float t = __builtin_amdgcn_rcpf(fmaf(0.3275911f, ax, 1.0f));
  float p = fmaf(fmaf(fmaf(fmaf(1.061405429f, t, -1.453152027f), t, 1.421413741f),
                      t, -0.284496736f), t, 0.254829592f);
  p *= t;
  float e = __expf(-ax * ax);
  float r = fmaf(-p, e, 1.0f);
  return __builtin_copysignf(r, x);
}

// block b handles row b: A1 = gamma*x + gamma*(1-gamma)*noise (bf16).
// Also zero-inits C1 (512K floats) and C2 (1M floats) for the atomic gemms.
__global__ __launch_bounds__(256, 2)
void prep_k(const float* __restrict__ x, const float* __restrict__ noise,
            const float* __restrict__ t, bf16_t* __restrict__ A1,
            float4* __restrict__ C1z, float4* __restrict__ C2z) {
  int b = blockIdx.x;
  int gid = b * 256 + threadIdx.x;           // 0..65535
  // zero C1 (131072 float4) + C2 (262144 float4)
  f32x4 z = (f32x4)0.0f;
#pragma unroll
  for (int i = 0; i < 2; ++i) *(f32x4*)&C1z[gid + i * 65536] = z;
#pragma unroll
  for (int i = 0; i < 4; ++i) *(f32x4*)&C2z[gid + i * 65536] = z;

  float tv = t[b];
  float p = exp2f(2.0f * tv * L2S);          // 1-gamma = 0.02^(2t)
  float g = 1.0f - p, gom = g * p;           // gamma, gamma*(1-gamma)
  int e = gid * 4;
  float4 xv = *(const float4*)(x + e);
  float4 nv = *(const float4*)(noise + e);
  bf16x4 o;
  o[0] = (__bf16)fmaf(gom, nv.x, g * xv.x);
  o[1] = (__bf16)fmaf(gom, nv.y, g * xv.y);
  o[2] = (__bf16)fmaf(gom, nv.z, g * xv.z);
  o[3] = (__bf16)fmaf(gom, nv.w, g * xv.w);
  *(bf16x4*)(A1 + e) = o;
}

// C += A[256 x Kchunk, bf16] @ W[Kchunk x N, f32->bf16], atomic f32 accumulation.
// BM=256, BN=32, BK=32. 4 waves, each 64(m)x32(n) = 4x2 frags of 16x16x32. [R6-proven body]
__global__ __launch_bounds__(256, 2)
void gemm_k(const bf16_t* __restrict__ A, int lda,
            const float* __restrict__ W, int N,
            float* __restrict__ C, int Ktiles, int Kchunk) {
  __shared__ bf16_t As[256 * LDK];
  __shared__ bf16_t Bs[32 * LDK];
  int tid = threadIdx.x;
  int lane = tid & 63, wave = tid >> 6;
  int n0 = blockIdx.x * 32;
  int k0 = blockIdx.z * Kchunk;
  int bn = tid & 31, bkg = tid >> 5;   // B staging: n (0..31), k-group of 4 (0..7)
  int fm = lane & 15, kq = lane >> 4;  // fragment lane decode

  f32x4 acc[4][2];
#pragma unroll
  for (int i = 0; i < 4; ++i)
#pragma unroll
    for (int j = 0; j < 2; ++j) acc[i][j] = (f32x4)0.0f;

  for (int kt = 0; kt < Ktiles; ++kt) {
    int kb = k0 + kt * 32;
    // stage A: thread = row, FULL BK=32: 4 x 8 bf16
    const bf16_t* Ar = A + (size_t)tid * lda + kb;
#pragma unroll
    for (int j = 0; j < 4; ++j)
      *(bf16x8*)(&As[tid * LDK + j * 8]) = *(const bf16x8*)(Ar + j * 8);
    // stage B transposed: Bs[n][k], fp32 -> bf16 during load (4 k-values/thread)
    {
      const float* Wp = W + (size_t)(kb + bkg * 4) * N + n0 + bn;
      bf16x4 bv;
#pragma unroll
      for (int i = 0; i < 4; ++i) bv[i] = (__bf16)Wp[(size_t)i * N];
      *(bf16x4*)(&Bs[bn * LDK + bkg * 4]) = bv;
    }
    __syncthreads();
    bf16x8 aF[4], bF[2];
#pragma unroll
    for (int i = 0; i < 4; ++i)
      aF[i] = *(const bf16x8*)(&As[(wave * 64 + i * 16 + fm) * LDK + kq * 8]);
#pragma unroll
    for (int j = 0; j < 2; ++j)
      bF[j] = *(const bf16x8*)(&Bs[(j * 16 + fm) * LDK + kq * 8]);
#pragma unroll
    for (int i = 0; i < 4; ++i)
#pragma unroll
      for (int j = 0; j < 2; ++j)
        acc[i][j] = __builtin_amdgcn_mfma_f32_16x16x32_bf16(aF[i], bF[j], acc[i][j], 0, 0, 0);
    __syncthreads();
  }
  // epilogue: atomic accumulate. C/D layout col=lane&15, row=(lane>>4)*4+reg [m89-verified]
  float* Cp = C + n0;
#pragma unroll
  for (int i = 0; i < 4; ++i) {
    int mrow = wave * 64 + i * 16 + kq * 4;
#pragma unroll
    for (int j = 0; j < 2; ++j)
#pragma unroll
      for (int r = 0; r < 4; ++r)
        unsafeAtomicAdd(&Cp[(size_t)(mrow + r) * N + j * 16 + fm], acc[i][j][r]);
  }
}

// h = leaky(C1 + t*W1[1024,:] + b1), stored bf16. Block 0 also zeroes out.
__global__ __launch_bounds__(256, 2)
void reduce1_k(const float* __restrict__ C1, const float* __restrict__ W1,
               const float* __restrict__ b1, const float* __restrict__ t,
               bf16_t* __restrict__ h, float* __restrict__ out) {
  if (blockIdx.x == 0 && threadIdx.x == 0) *out = 0.0f;  // consumed 2 dispatches later
  int e = (blockIdx.x * 256 + threadIdx.x) * 4;
  int b = e >> 11, n = e & 2047;
  float4 s = *(const float4*)(C1 + e);
  float tv = t[b];
  float4 wl = *(const float4*)(W1 + 1024 * 2048 + n);
  float4 bb = *(const float4*)(b1 + n);
  s.x += tv * wl.x + bb.x;
  s.y += tv * wl.y + bb.y;
  s.z += tv * wl.z + bb.z;
  s.w += tv * wl.w + bb.w;
  bf16x4 o;
  o[0] = (__bf16)(s.x >= 0.f ? s.x : 0.01f * s.x);
  o[1] = (__bf16)(s.y >= 0.f ? s.y : 0.01f * s.y);
  o[2] = (__bf16)(s.z >= 0.f ? s.z : 0.01f * s.z);
  o[3] = (__bf16)(s.w >= 0.f ? s.w : 0.01f * s.w);
  *(bf16x4*)(h + e) = o;
}

// one thread per element; row consts inline from t; C2 read (single slab),
// analytic erf bucket sum, weighted MSE.
__global__ __launch_bounds__(256, 4)
void loss_k(const float* __restrict__ x, const float* __restrict__ noise,
            const float* __restrict__ C2, const float* __restrict__ b2,
            const float* __restrict__ t, float* __restrict__ out) {
  int gid = blockIdx.x * 256 + threadIdx.x;  // 0..262143
  int b = gid >> 10, d = gid & 1023;
  float tv = t[b];
  float om = exp2f(2.0f * tv * L2S);         // 1-gamma
  float gamma = 1.0f - om;
  float r = sqrtf(om / gamma);
  float w = 1.0f / om;                       // SIGMA1^(-2t)
  bool lowt = tv < 1e-10f;
  int base2 = b * 2048 + d;
  float me = C2[base2] + b2[d];
  float lg = C2[base2 + 1024] + b2[1024 + d];
  float xs = x[gid], ns = noise[gid];

  float mu_x = xs + om * ns - r * me;        // mu/gamma - r*mu_eps
  float sig = r * __expf(lg);
  if (lowt) { mu_x = 0.f; sig = 1.f; }
  float invs = 0.70710678118654752f / sig;   // 1/(sigma*sqrt(2))
  float a = invs * 0.015625f;                // z step per k
  float c0 = (1.f + mu_x) * invs;            // z_k = a*k - c0
  // window |z|<3.5 for the k=1..126 interior sum; saturated tails counted exactly
  float m64 = 64.f * (1.f + mu_x);
  float wdt = 316.78383797157331f * sig;     // 3.5/a = 224*sqrt(2)*sig
  float lo = m64 - wdt, hi = m64 + wdt;
  int klo = (lo < 1.f) ? 1 : ((lo > 126.f) ? 127 : (int)ceilf(lo));
  int khi = (hi < 1.f) ? 0 : ((hi > 126.f) ? 126 : (int)floorf(hi));
  float ss = (float)(126 - khi) - (float)(klo - 1);  // erf=+1 above window, -1 below
  if (khi >= klo) {
    if (a <= 1.0f) {
      // Euler-Maclaurin midpoint: sum ~ (1/a)[G(zb)-G(za)] - (a/(12 sqrt(pi)))(eb-ea)
      float za = fmaf(a, (float)klo - 0.5f, -c0);
      float zb = fmaf(a, (float)khi + 0.5f, -c0);
      const float ISP = 0.56418958354775628f;  // 1/sqrt(pi)
      float ea = __expf(-za * za), eb = __expf(-zb * zb);
      float Ga = fmaf(za, erf_f(za), ISP * ea); // G(z)=z*erf(z)+e^{-z^2}/sqrt(pi), G'=erf
      float Gb = fmaf(zb, erf_f(zb), ISP * eb);
      float S = (Gb - Ga) * __builtin_amdgcn_rcpf(a)
              - a * 0.047015889f * (eb - ea);   // 1/(12*sqrt(pi))
      ss += S;
    } else {
      for (int k = klo; k <= khi; ++k) ss += erf_f(fmaf(a, (float)k, -c0));
    }
  }
  // non-saturated right edge term at k=127 (kr_127 = 63/64 < 1, not clamped)
  float z127 = fmaf(a, 127.f, -c0);
  float pO = fmaf(0.48828125f, 1.f + erf_f(z127),      // (125/256)(1+erf(z127))
                  fmaf(-0.0078125f, ss, -0.984375f));  // -(1/128)ss - 126/128
  float df = xs - pO;
  float accv = w * df * df;
#pragma unroll
  for (int off = 32; off > 0; off >>= 1) accv += __shfl_down(accv, off, 64);
  __shared__ float red[4];
  if ((threadIdx.x & 63) == 0) red[threadIdx.x >> 6] = accv;
  __syncthreads();
  if (threadIdx.x == 0) {
    const float SCALE = 3.9120230054281461f / 262144.0f;  // -ln(0.02)/(B*D)
    atomicAdd(out, (red[0] + red[1] + red[2] + red[3]) * SCALE);
  }
}

extern "C" void kernel_launch(void* const* d_in, const int* in_sizes, int n_in,
                              void* d_out, int out_size, void* d_ws, size_t ws_size,
                              hipStream_t stream) {
  const float* x     = (const float*)d_in[0];
  const float* t     = (const float*)d_in[1];
  const float* noise = (const float*)d_in[2];
  const float* W1    = (const float*)d_in[3];
  const float* b1    = (const float*)d_in[4];
  const float* W2    = (const float*)d_in[5];
  const float* b2    = (const float*)d_in[6];
  float* out = (float*)d_out;

  // ws layout (needs ~7.5 MB)
  char* ws = (char*)d_ws;
  bf16_t* A1 = (bf16_t*)ws;                        // 512 KB
  bf16_t* h  = (bf16_t*)(ws + 524288);             // 1 MB
  float*  C1 = (float*)(ws + 524288 + 1048576);    // 2 MB (256 x 2048 f32)
  float*  C2 = (float*)(ws + 524288 + 1048576 + 2097152);  // 4 MB (256 x 2048 x2... 256x2048 f32 x1? no: 2*D=2048 cols -> 2 MB; keep 4 MB reserved)

  prep_k<<<256, 256, 0, stream>>>(x, noise, t, A1, (float4*)C1, (float4*)C2);
  gemm_k<<<dim3(64, 1, 8), 256, 0, stream>>>(A1, 1024, W1, 2048, C1, 4, 128);
  reduce1_k<<<512, 256, 0, stream>>>(C1, W1, b1, t, h, out);
  gemm_k<<<dim3(64, 1, 8), 256, 0, stream>>>(h, 2048, W2, 2048, C2, 8, 256);
  loss_k<<<1024, 256, 0, stream>>>(x, noise, C2, b2, t, out);
}

// Round 13
// 123.817 us; speedup vs baseline: 2.7897x; 1.1269x over previous
//
#include <hip/hip_runtime.h>
#include <hip/hip_bf16.h>
#include <math.h>

// DiscretisedBNF loss, MI355X gfx950.
// R13: byte-exact revert to R10 (proven 124.7 us) after R12's atomic-splitK regression
//      (+15 us: scalar atomic RMW epilogue + L2 line contention; the "saved" partial
//      traffic was L3-resident all along — Infinity Cache absorption gotcha).
// Structure: prep(A1 bf16) -> GEMM1(splitK=8) -> reduce1(+out=0) -> GEMM2(splitK=8) -> loss.
// Abel summation (k=127 edge kept un-saturated):
//   pO = (125/256)(1+erf(z_127)) - 126/128 - (1/128) sum_{k=1..126} erf(z_k),
//   z_k = (k/64 - 1 - mu_x) / (sigma*sqrt(2)).
// Interior sum via Euler-Maclaurin midpoint (O(1)); a>1 -> direct sum (<=7 terms).
// Session ledger: coop grid.sync ~60us/sync (R11); prep-in-gemm fusion costs 128MB
// redundant reads (R9); atomics regress (R12); BN=32@2blk/CU -3us (R6); loss O(1) -3us (R8).

typedef __bf16 bf16_t;
typedef __bf16 bf16x8 __attribute__((ext_vector_type(8)));
typedef __bf16 bf16x4 __attribute__((ext_vector_type(4)));
typedef float  f32x4  __attribute__((ext_vector_type(4)));

#define LDK 40  // LDS row stride in bf16 (32 + 8 pad): 80B rows, 16B-aligned
#define L2S -5.6438561897747248f  // log2(0.02)

// Abramowitz-Stegun 7.1.26, |abs err| <= 1.5e-7, branch-free full-range.
__device__ __forceinline__ float erf_f(float x) {
  float ax = __builtin_fabsf(x);
  float t = __builtin_amdgcn_rcpf(fmaf(0.3275911f, ax, 1.0f));
  float p = fmaf(fmaf(fmaf(fmaf(1.061405429f, t, -1.453152027f), t, 1.421413741f),
                      t, -0.284496736f), t, 0.254829592f);
  p *= t;
  float e = __expf(-ax * ax);
  float r = fmaf(-p, e, 1.0f);
  return __builtin_copysignf(r, x);
}

// block b handles row b (1024 elems, 256 thr x 4): A1 = gamma*x + gamma*(1-gamma)*noise, bf16.
__global__ __launch_bounds__(256, 2)
void prep_k(const float* __restrict__ x, const float* __restrict__ noise,
            const float* __restrict__ t, bf16_t* __restrict__ A1) {
  int b = blockIdx.x;
  float tv = t[b];
  float p = exp2f(2.0f * tv * L2S);        // 1-gamma = 0.02^(2t)
  float g = 1.0f - p, gom = g * p;         // gamma, gamma*(1-gamma)
  int e = (b * 256 + threadIdx.x) * 4;
  float4 xv = *(const float4*)(x + e);
  float4 nv = *(const float4*)(noise + e);
  bf16x4 o;
  o[0] = (__bf16)fmaf(gom, nv.x, g * xv.x);
  o[1] = (__bf16)fmaf(gom, nv.y, g * xv.y);
  o[2] = (__bf16)fmaf(gom, nv.z, g * xv.z);
  o[3] = (__bf16)fmaf(gom, nv.w, g * xv.w);
  *(bf16x4*)(A1 + e) = o;
}

// P[z] = A[256 x Kchunk, bf16] @ W[Kchunk x N, f32->bf16].
// BM=256, BN=32, BK=32. 4 waves, each 64(m)x32(n) = 4x2 frags of 16x16x32. [R6-proven]
__global__ __launch_bounds__(256, 2)
void gemm_k(const bf16_t* __restrict__ A, int lda,
            const float* __restrict__ W, int N,
            float* __restrict__ P, int Ktiles, int Kchunk) {
  __shared__ bf16_t As[256 * LDK];
  __shared__ bf16_t Bs[32 * LDK];
  int tid = threadIdx.x;
  int lane = tid & 63, wave = tid >> 6;
  int n0 = blockIdx.x * 32;
  int k0 = blockIdx.z * Kchunk;
  int bn = tid & 31, bkg = tid >> 5;   // B staging: n (0..31), k-group of 4 (0..7)
  int fm = lane & 15, kq = lane >> 4;  // fragment lane decode

  f32x4 acc[4][2];
#pragma unroll
  for (int i = 0; i < 4; ++i)
#pragma unroll
    for (int j = 0; j < 2; ++j) acc[i][j] = (f32x4)0.0f;

  for (int kt = 0; kt < Ktiles; ++kt) {
    int kb = k0 + kt * 32;
    // stage A: thread = row, FULL BK=32: 4 x 8 bf16
    const bf16_t* Ar = A + (size_t)tid * lda + kb;
#pragma unroll
    for (int j = 0; j < 4; ++j)
      *(bf16x8*)(&As[tid * LDK + j * 8]) = *(const bf16x8*)(Ar + j * 8);
    // stage B transposed: Bs[n][k], fp32 -> bf16 during load (4 k-values/thread)
    {
      const float* Wp = W + (size_t)(kb + bkg * 4) * N + n0 + bn;
      bf16x4 bv;
#pragma unroll
      for (int i = 0; i < 4; ++i) bv[i] = (__bf16)Wp[(size_t)i * N];
      *(bf16x4*)(&Bs[bn * LDK + bkg * 4]) = bv;
    }
    __syncthreads();
    bf16x8 aF[4], bF[2];
#pragma unroll
    for (int i = 0; i < 4; ++i)
      aF[i] = *(const bf16x8*)(&As[(wave * 64 + i * 16 + fm) * LDK + kq * 8]);
#pragma unroll
    for (int j = 0; j < 2; ++j)
      bF[j] = *(const bf16x8*)(&Bs[(j * 16 + fm) * LDK + kq * 8]);
#pragma unroll
    for (int i = 0; i < 4; ++i)
#pragma unroll
      for (int j = 0; j < 2; ++j)
        acc[i][j] = __builtin_amdgcn_mfma_f32_16x16x32_bf16(aF[i], bF[j], acc[i][j], 0, 0, 0);
    __syncthreads();
  }
  // epilogue: C/D layout col=lane&15, row=(lane>>4)*4+reg  [m89-verified]
  float* Pp = P + (size_t)blockIdx.z * 256 * N + n0;
#pragma unroll
  for (int i = 0; i < 4; ++i) {
    int mrow = wave * 64 + i * 16 + kq * 4;
#pragma unroll
    for (int j = 0; j < 2; ++j)
#pragma unroll
      for (int r = 0; r < 4; ++r)
        Pp[(size_t)(mrow + r) * N + j * 16 + fm] = acc[i][j][r];
  }
}

// h = leaky(sum_s P1[s] + t*W1[1024,:] + b1), stored bf16. Block 0 also zeroes out.
__global__ __launch_bounds__(256, 2)
void reduce1_k(const float* __restrict__ P1, const float* __restrict__ W1,
               const float* __restrict__ b1, const float* __restrict__ t,
               bf16_t* __restrict__ h, float* __restrict__ out) {
  if (blockIdx.x == 0 && threadIdx.x == 0) *out = 0.0f;  // consumed 2 dispatches later
  int e = (blockIdx.x * 256 + threadIdx.x) * 4;
  int b = e >> 11, n = e & 2047;
  float4 s = *(const float4*)(P1 + e);
#pragma unroll
  for (int sp = 1; sp < 8; ++sp) {
    float4 v = *(const float4*)(P1 + (size_t)sp * 524288 + e);
    s.x += v.x; s.y += v.y; s.z += v.z; s.w += v.w;
  }
  float tv = t[b];
  float4 wl = *(const float4*)(W1 + 1024 * 2048 + n);
  float4 bb = *(const float4*)(b1 + n);
  s.x += tv * wl.x + bb.x;
  s.y += tv * wl.y + bb.y;
  s.z += tv * wl.z + bb.z;
  s.w += tv * wl.w + bb.w;
  bf16x4 o;
  o[0] = (__bf16)(s.x >= 0.f ? s.x : 0.01f * s.x);
  o[1] = (__bf16)(s.y >= 0.f ? s.y : 0.01f * s.y);
  o[2] = (__bf16)(s.z >= 0.f ? s.z : 0.01f * s.z);
  o[3] = (__bf16)(s.w >= 0.f ? s.w : 0.01f * s.w);
  *(bf16x4*)(h + e) = o;
}

// one thread per element; row consts inline from t; reduce GEMM2 partials,
// analytic erf bucket sum, weighted MSE.
__global__ __launch_bounds__(256, 4)
void loss_k(const float* __restrict__ x, const float* __restrict__ noise,
            const float* __restrict__ P2, const float* __restrict__ b2,
            const float* __restrict__ t, float* __restrict__ out) {
  int gid = blockIdx.x * 256 + threadIdx.x;  // 0..262143
  int b = gid >> 10, d = gid & 1023;
  float tv = t[b];
  float om = exp2f(2.0f * tv * L2S);         // 1-gamma
  float gamma = 1.0f - om;
  float r = sqrtf(om / gamma);
  float w = 1.0f / om;                       // SIGMA1^(-2t)
  bool lowt = tv < 1e-10f;
  int base2 = b * 2048 + d;
  float me = b2[d], lg = b2[1024 + d];
#pragma unroll
  for (int sp = 0; sp < 8; ++sp) {
    me += P2[(size_t)sp * 524288 + base2];
    lg += P2[(size_t)sp * 524288 + base2 + 1024];
  }
  float xs = x[gid], ns = noise[gid];

  float mu_x = xs + om * ns - r * me;        // mu/gamma - r*mu_eps
  float sig = r * __expf(lg);
  if (lowt) { mu_x = 0.f; sig = 1.f; }
  float invs = 0.70710678118654752f / sig;   // 1/(sigma*sqrt(2))
  float a = invs * 0.015625f;                // z step per k
  float c0 = (1.f + mu_x) * invs;            // z_k = a*k - c0
  // window |z|<3.5 for the k=1..126 interior sum; saturated tails counted exactly
  float m64 = 64.f * (1.f + mu_x);
  float wdt = 316.78383797157331f * sig;     // 3.5/a = 224*sqrt(2)*sig
  float lo = m64 - wdt, hi = m64 + wdt;
  int klo = (lo < 1.f) ? 1 : ((lo > 126.f) ? 127 : (int)ceilf(lo));
  int khi = (hi < 1.f) ? 0 : ((hi > 126.f) ? 126 : (int)floorf(hi));
  float ss = (float)(126 - khi) - (float)(klo - 1);  // erf=+1 above window, -1 below
  if (khi >= klo) {
    if (a <= 1.0f) {
      // Euler-Maclaurin midpoint: sum ~ (1/a)[G(zb)-G(za)] - (a/(12 sqrt(pi)))(eb-ea)
      float za = fmaf(a, (float)klo - 0.5f, -c0);
      float zb = fmaf(a, (float)khi + 0.5f, -c0);
      const float ISP = 0.56418958354775628f;  // 1/sqrt(pi)
      float ea = __expf(-za * za), eb = __expf(-zb * zb);
      float Ga = fmaf(za, erf_f(za), ISP * ea); // G(z)=z*erf(z)+e^{-z^2}/sqrt(pi), G'=erf
      float Gb = fmaf(zb, erf_f(zb), ISP * eb);
      float S = (Gb - Ga) * __builtin_amdgcn_rcpf(a)
              - a * 0.047015889f * (eb - ea);   // 1/(12*sqrt(pi))
      ss += S;
    } else {
      for (int k = klo; k <= khi; ++k) ss += erf_f(fmaf(a, (float)k, -c0));
    }
  }
  // non-saturated right edge term at k=127 (kr_127 = 63/64 < 1, not clamped)
  float z127 = fmaf(a, 127.f, -c0);
  float pO = fmaf(0.48828125f, 1.f + erf_f(z127),      // (125/256)(1+erf(z127))
                  fmaf(-0.0078125f, ss, -0.984375f));  // -(1/128)ss - 126/128
  float df = xs - pO;
  float accv = w * df * df;
#pragma unroll
  for (int off = 32; off > 0; off >>= 1) accv += __shfl_down(accv, off, 64);
  __shared__ float red[4];
  if ((threadIdx.x & 63) == 0) red[threadIdx.x >> 6] = accv;
  __syncthreads();
  if (threadIdx.x == 0) {
    const float SCALE = 3.9120230054281461f / 262144.0f;  // -ln(0.02)/(B*D)
    atomicAdd(out, (red[0] + red[1] + red[2] + red[3]) * SCALE);
  }
}

extern "C" void kernel_launch(void* const* d_in, const int* in_sizes, int n_in,
                              void* d_out, int out_size, void* d_ws, size_t ws_size,
                              hipStream_t stream) {
  const float* x     = (const float*)d_in[0];
  const float* t     = (const float*)d_in[1];
  const float* noise = (const float*)d_in[2];
  const float* W1    = (const float*)d_in[3];
  const float* b1    = (const float*)d_in[4];
  const float* W2    = (const float*)d_in[5];
  const float* b2    = (const float*)d_in[6];
  float* out = (float*)d_out;

  // ws layout (needs ~34 MB)
  char* ws = (char*)d_ws;
  bf16_t* A1 = (bf16_t*)ws;                        // 512 KB
  bf16_t* h  = (bf16_t*)(ws + 524288);             // 1 MB
  float*  P1 = (float*)(ws + 524288 + 1048576);    // 16 MB
  float*  P2 = (float*)(ws + 524288 + 1048576 + 16777216);  // 16 MB

  prep_k<<<256, 256, 0, stream>>>(x, noise, t, A1);
  gemm_k<<<dim3(64, 1, 8), 256, 0, stream>>>(A1, 1024, W1, 2048, P1, 4, 128);
  reduce1_k<<<512, 256, 0, stream>>>(P1, W1, b1, t, h, out);
  gemm_k<<<dim3(64, 1, 8), 256, 0, stream>>>(h, 2048, W2, 2048, P2, 8, 256);
  loss_k<<<1024, 256, 0, stream>>>(x, noise, P2, b2, t, out);
}